// Round 4
// baseline (10.210 us; speedup 1.0000x reference)
//
#include <hip/hip_runtime.h>

#define HH 128
#define WW 128
#define NIMG 84      // B*C = 4*21
#define BAND 8       // output rows per block
#define GR (BAND + 4)

// Closed form of the reference FW loop (done fires at t=1, freezing v = s_0):
//   out = -beta + energy_pool(sigmoid(beta))
// energy_pool = separable 5-tap stencil (weights N(i,u) x N(j,v)) minus
// self term cnt*g, with N(a,b) = max(0, min(a,b,125) - max(a-2,b-2,0) + 1).
// Interior 1D weights: (1,2,3,2,1). Boundary deviations only at a in {0,1,126,127}.
__global__ __launch_bounds__(256, 8) void crf_onestep(const float* __restrict__ beta,
                                                      float* __restrict__ out) {
    __shared__ float gL[GR][WW];     // sigmoid(beta), 6 KB
    __shared__ float tL[GR][WW];     // row-stencil intermediate, 6 KB
    __shared__ float bL[BAND][WW];   // beta for the 8 output rows, 4 KB

    const int img = blockIdx.x;      // 0..83
    const int band = blockIdx.y;     // 0..15
    const int r0 = band * BAND;
    const int tid = threadIdx.x;
    const int tx = tid & 31;         // float4 column group: cols 4tx..4tx+3
    const int ty = tid >> 5;         // 0..7
    const int c0 = tx << 2;

    const float* __restrict__ bimg = beta + (size_t)img * (HH * WW);
    float* __restrict__ oimg = out + (size_t)img * (HH * WW);

    // ---- stage g = sigmoid(beta), staged rows 0..11 = image rows r0-2..r0+9
#pragma unroll
    for (int rr = 0; rr < GR; rr += 8) {
        int r = rr + ty;
        if (r < GR) {
            int ic = min(max(r0 + r - 2, 0), HH - 1);  // clamp; OOB weight=0 later
            float4 b = *(const float4*)&bimg[ic * WW + c0];
            float4 g;
            g.x = 1.0f / (1.0f + __expf(-b.x));
            g.y = 1.0f / (1.0f + __expf(-b.y));
            g.z = 1.0f / (1.0f + __expf(-b.z));
            g.w = 1.0f / (1.0f + __expf(-b.w));
            *(float4*)&gL[r][c0] = g;
            if (r >= 2 && r < 2 + BAND) *(float4*)&bL[r - 2][c0] = b;
        }
    }
    __syncthreads();

    // ---- row pass: tL[r][j] = sum_v N(j,v) gL[r][v]
#pragma unroll
    for (int rr = 0; rr < GR; rr += 8) {
        int r = rr + ty;
        if (r < GR) {
            float s[12];  // cols c0-4 .. c0+7 (clamped reads; fixed up below)
            *(float4*)&s[0] = *(const float4*)&gL[r][max(c0 - 4, 0)];
            *(float4*)&s[4] = *(const float4*)&gL[r][c0];
            *(float4*)&s[8] = *(const float4*)&gL[r][min(c0 + 4, WW - 4)];
            float t[4];
#pragma unroll
            for (int k = 0; k < 4; ++k)
                t[k] = s[k + 2] + 2.f * s[k + 3] + 3.f * s[k + 4] +
                       2.f * s[k + 5] + s[k + 6];
            if (tx == 0) {   // j=0: w(0,0..2)=(1,1,1); j=1: w(1,0..3)=(1,2,2,1)
                t[0] = s[4] + s[5] + s[6];
                t[1] = s[4] + 2.f * s[5] + 2.f * s[6] + s[7];
            }
            if (tx == 31) {  // j=126: w(126,124..127)=(1,2,2,1); j=127: (1,1,1)
                t[2] = s[4] + 2.f * s[5] + 2.f * s[6] + s[7];
                t[3] = s[5] + s[6] + s[7];
            }
            *(float4*)&tL[r][c0] = *(const float4*)&t[0];
        }
    }
    __syncthreads();

    // ---- column pass + closed-form output: one row per thread
    {
        const int i = r0 + ty;           // image row; staged index ty+2
        float4 colsum = {0.f, 0.f, 0.f, 0.f};
        float ci = 3.0f;                 // N(i,i)
#pragma unroll
        for (int d = 0; d < 5; ++d) {
            int u = i + d - 2;
            int lo = max(max(i, u) - 2, 0);
            int hi = min(min(i, u), HH - 3);
            float w = (float)max(0, hi - lo + 1);
            if (d == 2) ci = w;
            float4 tv = *(const float4*)&tL[ty + d][c0];
            colsum.x += w * tv.x; colsum.y += w * tv.y;
            colsum.z += w * tv.z; colsum.w += w * tv.w;
        }
        float4 cj = {3.f, 3.f, 3.f, 3.f};   // N(j,j)
        if (tx == 0)  { cj.x = 1.f; cj.y = 2.f; }
        if (tx == 31) { cj.z = 2.f; cj.w = 1.f; }
        float4 g = *(const float4*)&gL[ty + 2][c0];
        float4 b = *(const float4*)&bL[ty][c0];
        float4 o;
        o.x = -b.x + (colsum.x - ci * cj.x * g.x);
        o.y = -b.y + (colsum.y - ci * cj.y * g.y);
        o.z = -b.z + (colsum.z - ci * cj.z * g.z);
        o.w = -b.w + (colsum.w - ci * cj.w * g.w);
        *(float4*)&oimg[i * WW + c0] = o;
    }
}

extern "C" void kernel_launch(void* const* d_in, const int* in_sizes, int n_in,
                              void* d_out, int out_size, void* d_ws, size_t ws_size,
                              hipStream_t stream) {
    const float* beta = (const float*)d_in[0];
    float* out = (float*)d_out;
    (void)in_sizes; (void)n_in; (void)d_ws; (void)ws_size; (void)out_size;
    dim3 grid(NIMG, HH / BAND);
    crf_onestep<<<grid, 256, 0, stream>>>(beta, out);
}